// Round 9
// baseline (197.353 us; speedup 1.0000x reference)
//
#include <hip/hip_runtime.h>
#include <stdint.h>

typedef float f32x4 __attribute__((ext_vector_type(4)));
typedef __bf16 bf16x8 __attribute__((ext_vector_type(8)));
typedef unsigned short u16;
typedef unsigned int u32;

#define N_NODES 8192
#define F_IN 512
#define F_OUT 128
#define LRA 0.2f
#define JS 8
#define JLEN (N_NODES / JS)   // 1024
#define NU (JLEN / 32)        // 32 units of 32 cols

__device__ __forceinline__ u16 f32_to_bf16(float f) {
  union { float f; u32 u; } v; v.f = f;
  u32 u = v.u;
  u += 0x7fffu + ((u >> 16) & 1u);   // round-to-nearest-even
  return (u16)(u >> 16);
}
__device__ __forceinline__ float dot4(f32x4 a, f32x4 b) {
  return a[0] * b[0] + a[1] * b[1] + a[2] * b[2] + a[3] * b[3];
}

// ---------------------------------------------------------------------------
// prep_k: WT[d][k] = bf16(W[k][d])  (128 x 512), and wa = [W@a1 ; W@a2] fp32.
// ---------------------------------------------------------------------------
__global__ __launch_bounds__(256) void prep_k(
    const float* __restrict__ W, const float* __restrict__ av,
    u16* __restrict__ WT, float* __restrict__ wa) {
  __shared__ u16 Ts[F_OUT][40];
  const int t = threadIdx.x, kc = (int)blockIdx.x * 32;
  {
    const int k = t >> 3, dof = (t & 7) * 16;
#pragma unroll
    for (int q = 0; q < 4; ++q) {
      f32x4 v = *(const f32x4*)&W[(size_t)(kc + k) * F_OUT + dof + q * 4];
#pragma unroll
      for (int e = 0; e < 4; ++e) Ts[dof + q * 4 + e][k] = f32_to_bf16(v[e]);
    }
  }
  __syncthreads();
  {
    const int d = t >> 1, kh = (t & 1) * 16;
    uint4 o0 = *(uint4*)&Ts[d][kh];
    uint4 o1 = *(uint4*)&Ts[d][kh + 8];
    *(uint4*)&WT[(size_t)d * F_IN + kc + kh] = o0;
    *(uint4*)&WT[(size_t)d * F_IN + kc + kh + 8] = o1;
  }
  {
    const int kl = t >> 3, l8 = t & 7;
    const float* wrow = &W[(size_t)(kc + kl) * F_OUT];
    float s1 = 0.f, s2 = 0.f;
#pragma unroll
    for (int q = 0; q < 2; ++q) {
      int dd = l8 * 16 + q * 8;
      f32x4 w0 = *(const f32x4*)&wrow[dd];
      f32x4 w1 = *(const f32x4*)&wrow[dd + 4];
      s1 += dot4(w0, *(const f32x4*)&av[dd]) + dot4(w1, *(const f32x4*)&av[dd + 4]);
      s2 += dot4(w0, *(const f32x4*)&av[F_OUT + dd]) + dot4(w1, *(const f32x4*)&av[F_OUT + dd + 4]);
    }
#pragma unroll
    for (int m = 1; m <= 4; m <<= 1) {
      s1 += __shfl_xor(s1, m, 64);
      s2 += __shfl_xor(s2, m, 64);
    }
    if (l8 == 0) { wa[kc + kl] = s1; wa[F_IN + kc + kl] = s2; }
  }
}

// ---------------------------------------------------------------------------
// gemm_wh: WhT[d][i] = bf16( (h @ W)[i][d] ) via 16x16x32 bf16 MFMA.
// Wh1/Wh2 computed EXACTLY in fp32 as h @ (W@a) fused into A-staging.
// ---------------------------------------------------------------------------
__global__ __launch_bounds__(256) void gemm_wh(
    const float* __restrict__ h, const u16* __restrict__ WT,
    const float* __restrict__ wa,
    u16* __restrict__ WhT, float* __restrict__ Wh1, float* __restrict__ Wh2) {
  __shared__ u16 Ab[2][32][80];
  __shared__ u16 Bs[2][F_OUT][80];
  const int t = threadIdx.x;
  const int i0 = (int)blockIdx.x * 32;
  const int w = t >> 6, l = t & 63, r = l & 15, oct = l >> 4;
  const int mrow = (w & 1) * 16, ncol = (w >> 1) * 64;
  const int ar = t >> 3, ak = (t & 7) * 8;
  const int br = t >> 1, bk = (t & 1) * 32;

  const float* hrow = &h[(size_t)(i0 + ar) * F_IN + ak];
  const u16* wtrow = &WT[(size_t)br * F_IN + bk];
  const float* wap = &wa[ak];
  const float* wbp = &wa[F_IN + ak];

  f32x4 acc[4];
#pragma unroll
  for (int nf = 0; nf < 4; ++nf) acc[nf] = (f32x4){0.f, 0.f, 0.f, 0.f};
  float s1 = 0.f, s2 = 0.f;

  f32x4 ra0, ra1;
  uint4 rb[4];

#define STORE_A(B)                                                        \
  { u32 p0 = f32_to_bf16(ra0[0]) | ((u32)f32_to_bf16(ra0[1]) << 16);      \
    u32 p1 = f32_to_bf16(ra0[2]) | ((u32)f32_to_bf16(ra0[3]) << 16);      \
    u32 p2 = f32_to_bf16(ra1[0]) | ((u32)f32_to_bf16(ra1[1]) << 16);      \
    u32 p3 = f32_to_bf16(ra1[2]) | ((u32)f32_to_bf16(ra1[3]) << 16);      \
    uint4 v; v.x = p0; v.y = p1; v.z = p2; v.w = p3;                      \
    *(uint4*)&Ab[B][ar][ak] = v; }
#define STORE_B(B)                                                        \
  { *(uint4*)&Bs[B][br][bk + 0]  = rb[0];                                 \
    *(uint4*)&Bs[B][br][bk + 8]  = rb[1];                                 \
    *(uint4*)&Bs[B][br][bk + 16] = rb[2];                                 \
    *(uint4*)&Bs[B][br][bk + 24] = rb[3]; }

  ra0 = *(const f32x4*)&hrow[0];
  ra1 = *(const f32x4*)&hrow[4];
#pragma unroll
  for (int j = 0; j < 4; ++j) rb[j] = *(const uint4*)&wtrow[j * 8];
  s1 += dot4(ra0, *(const f32x4*)&wap[0]) + dot4(ra1, *(const f32x4*)&wap[4]);
  s2 += dot4(ra0, *(const f32x4*)&wbp[0]) + dot4(ra1, *(const f32x4*)&wbp[4]);
  STORE_A(0); STORE_B(0);
  __syncthreads();

#pragma unroll
  for (int it = 0; it < 8; ++it) {
    const int buf = it & 1;
    if (it < 7) {
      const int kc = (it + 1) * 64;
      ra0 = *(const f32x4*)&hrow[kc];
      ra1 = *(const f32x4*)&hrow[kc + 4];
#pragma unroll
      for (int j = 0; j < 4; ++j) rb[j] = *(const uint4*)&wtrow[kc + j * 8];
      s1 += dot4(ra0, *(const f32x4*)&wap[kc]) + dot4(ra1, *(const f32x4*)&wap[kc + 4]);
      s2 += dot4(ra0, *(const f32x4*)&wbp[kc]) + dot4(ra1, *(const f32x4*)&wbp[kc + 4]);
    }
#pragma unroll
    for (int ks = 0; ks < 2; ++ks) {
      bf16x8 af = *(bf16x8*)&Ab[buf][mrow + r][ks * 32 + oct * 8];
#pragma unroll
      for (int nf = 0; nf < 4; ++nf) {
        bf16x8 bfv = *(bf16x8*)&Bs[buf][ncol + nf * 16 + r][ks * 32 + oct * 8];
        acc[nf] = __builtin_amdgcn_mfma_f32_16x16x32_bf16(af, bfv, acc[nf], 0, 0, 0);
      }
    }
    if (it < 7) {
      STORE_A(buf ^ 1); STORE_B(buf ^ 1);
      __syncthreads();
    }
  }
#undef STORE_A
#undef STORE_B

#pragma unroll
  for (int m = 1; m <= 4; m <<= 1) {
    s1 += __shfl_xor(s1, m, 64);
    s2 += __shfl_xor(s2, m, 64);
  }
  if ((t & 7) == 0) { Wh1[i0 + ar] = s1; Wh2[i0 + ar] = s2; }

#pragma unroll
  for (int nf = 0; nf < 4; ++nf) {
    u32 lo = f32_to_bf16(acc[nf][0]) | ((u32)f32_to_bf16(acc[nf][1]) << 16);
    u32 hi = f32_to_bf16(acc[nf][2]) | ((u32)f32_to_bf16(acc[nf][3]) << 16);
    const int d = ncol + nf * 16 + r;
    uint2 v; v.x = lo; v.y = hi;
    *(uint2*)&WhT[(size_t)d * N_NODES + i0 + mrow + oct * 4] = v;
  }
}

// ---------------------------------------------------------------------------
// gat_main v9: barrier-free reg-direct pipeline with vmcnt-FIFO-correct issue
// order. Per 32-col unit k, the body issues bv(k+1) (L2, ping-pong regs)
// BEFORE adj(k+2) (HBM, 4 rotating reg sets, unrolled x4 -> static indices).
// Because vmcnt retires in issue order, the MFMA's wait for bv(k) (issued
// last iter, BEFORE adj(k+1)) leaves adj(k+1) in flight -> adj gets 2 full
// iteration-times (~1000cy) of latency cover; bv gets 1 (~500cy >= L2).
// sched_barrier(0) pins the two issue groups. No barriers, no LDS P tile.
// Denominator accumulated from the SAME rounded bf16 P values.
// ---------------------------------------------------------------------------
__global__ __launch_bounds__(256) void gat_main(
    const int* __restrict__ adj, const float* __restrict__ Wh1,
    const float* __restrict__ Wh2, const u16* __restrict__ WhT,
    float* __restrict__ accp, float* __restrict__ sp) {
  __shared__ float w2s[JLEN];

  const int t = threadIdx.x;
  const int jsi = (int)blockIdx.x & (JS - 1);   // jsi == XCD -> slice L2-pinned
  const int bi = (int)blockIdx.x >> 3;
  const int j0 = jsi * JLEN;
  const int w = t >> 6, l = t & 63, r = l & 15, oct = l >> 4;
  const int i0w = bi * 64 + w * 16;             // wave's 16-row strip

  for (int k = t * 4; k < JLEN; k += 1024)
    *(f32x4*)&w2s[k] = *(const f32x4*)&Wh2[j0 + k];
  const float cI = Wh1[i0w + r];
  __syncthreads();                              // the only barrier (w2s)

  const int* ap = &adj[(size_t)(i0w + r) * N_NODES + j0 + oct * 8];
  const u16* vb = &WhT[(size_t)r * N_NODES + j0 + oct * 8];

  f32x4 acc[8];
#pragma unroll
  for (int nf = 0; nf < 8; ++nf) acc[nf] = (f32x4){0.f, 0.f, 0.f, 0.f};
  float sden = 0.f;

  bf16x8 bvA[8], bvB[8];
  int4 s0a, s0b, s1a, s1b, s2a, s2b, s3a, s3b;

#define LOAD_BV(BV, JC) do {                                                \
    _Pragma("unroll")                                                       \
    for (int nf = 0; nf < 8; ++nf)                                          \
      BV[nf] = *(const bf16x8*)(vb + (size_t)nf * 16 * N_NODES + (JC));     \
  } while (0)

#define COMPUTE(CA, CB, JC, BV) do {                                        \
    f32x4 wv0 = *(const f32x4*)&w2s[(JC) + oct * 8];                        \
    f32x4 wv1 = *(const f32x4*)&w2s[(JC) + oct * 8 + 4];                    \
    u32 pk_[4];                                                             \
    _Pragma("unroll")                                                       \
    for (int q = 0; q < 4; ++q) {                                           \
      int ma_ = (q == 0) ? CA.x : (q == 1) ? CA.z : (q == 2) ? CB.x : CB.z; \
      int mb_ = (q == 0) ? CA.y : (q == 1) ? CA.w : (q == 2) ? CB.y : CB.w; \
      float wA_ = (q < 2) ? wv0[(q & 1) * 2] : wv1[(q & 1) * 2];            \
      float wB_ = (q < 2) ? wv0[(q & 1) * 2 + 1] : wv1[(q & 1) * 2 + 1];    \
      float xA_ = cI + wA_; xA_ = fmaxf(xA_, LRA * xA_);                    \
      float xB_ = cI + wB_; xB_ = fmaxf(xB_, LRA * xB_);                    \
      float pA_ = ma_ ? __expf(xA_) : 0.f;                                  \
      float pB_ = mb_ ? __expf(xB_) : 0.f;                                  \
      u32 uA_ = f32_to_bf16(pA_), uB_ = f32_to_bf16(pB_);                   \
      union { u32 u; float f; } fA_, fB_;                                   \
      fA_.u = uA_ << 16; fB_.u = uB_ << 16;                                 \
      sden += fA_.f + fB_.f;                                                \
      pk_[q] = uA_ | (uB_ << 16);                                           \
    }                                                                       \
    union { u32 u[4]; bf16x8 v; } cv_;                                      \
    cv_.u[0] = pk_[0]; cv_.u[1] = pk_[1];                                   \
    cv_.u[2] = pk_[2]; cv_.u[3] = pk_[3];                                   \
    _Pragma("unroll")                                                       \
    for (int nf = 0; nf < 8; ++nf)                                          \
      acc[nf] = __builtin_amdgcn_mfma_f32_16x16x32_bf16(cv_.v, BV[nf], acc[nf], 0, 0, 0); \
  } while (0)

  // STEP k: issue bv(k+1)->BVN, adj(k+2)->NX; compute adj(k)=CUR with BVC.
#define STEP(K, CURa, CURb, NXa, NXb, BVC, BVN) do {                        \
    const int k_ = (K);                                                     \
    const int jb_ = (k_ + 1 < NU) ? (k_ + 1) * 32 : 0;                      \
    LOAD_BV(BVN, jb_);                                                      \
    __builtin_amdgcn_sched_barrier(0);                                      \
    const int jn_ = (k_ + 2 < NU) ? (k_ + 2) * 32 : 0;                      \
    NXa = *(const int4*)(ap + jn_);                                         \
    NXb = *(const int4*)(ap + jn_ + 4);                                     \
    __builtin_amdgcn_sched_barrier(0);                                      \
    COMPUTE(CURa, CURb, k_ * 32, BVC);                                      \
  } while (0)

  // prologue: adj(0)->s0, adj(1)->s1, bv(0)->bvA
  s0a = *(const int4*)(ap + 0);
  s0b = *(const int4*)(ap + 4);
  s1a = *(const int4*)(ap + 32);
  s1b = *(const int4*)(ap + 36);
  LOAD_BV(bvA, 0);

#pragma unroll 1
  for (int u = 0; u < NU; u += 4) {
    STEP(u + 0, s0a, s0b, s2a, s2b, bvA, bvB);
    STEP(u + 1, s1a, s1b, s3a, s3b, bvB, bvA);
    STEP(u + 2, s2a, s2b, s0a, s0b, bvA, bvB);
    STEP(u + 3, s3a, s3b, s1a, s1b, bvB, bvA);
  }
#undef STEP
#undef COMPUTE
#undef LOAD_BV

  // ---- denominator: row r full sum across the 4 oct groups ----
  {
    float s = sden;
    s += __shfl_xor(s, 16, 64);
    s += __shfl_xor(s, 32, 64);
    if (l < 16) sp[(size_t)jsi * N_NODES + i0w + l] = s;
  }

  // ---- numerator partials: C frag col(d)=nf*16+r, row=oct*4+reg ----
  float* apw = &accp[((size_t)jsi * N_NODES + i0w + oct * 4) * F_OUT + r];
#pragma unroll
  for (int nf = 0; nf < 8; ++nf)
#pragma unroll
    for (int rr = 0; rr < 4; ++rr)
      apw[(size_t)rr * F_OUT + nf * 16] = acc[nf][rr];
}

// ---------------------------------------------------------------------------
// finalize: reduce j-split partials (f32x4 vectorized), divide, ELU.
// ---------------------------------------------------------------------------
__global__ __launch_bounds__(256) void finalize_k(
    const float* __restrict__ accp, const float* __restrict__ sp,
    float* __restrict__ out) {
  const int vidx = (int)blockIdx.x * 256 + threadIdx.x;   // f32x4 index
  const int i = vidx >> 5;                                // node row
  f32x4 num = (f32x4){0.f, 0.f, 0.f, 0.f};
  float den = 0.f;
#pragma unroll
  for (int s = 0; s < JS; ++s) {
    num += *((const f32x4*)accp + (size_t)s * (N_NODES * F_OUT / 4) + vidx);
    den += sp[(size_t)s * N_NODES + i];
  }
  f32x4 o;
#pragma unroll
  for (int c = 0; c < 4; ++c) {
    float x = num[c] / den;
    o[c] = x > 0.f ? x : expm1f(x);
  }
  *((f32x4*)out + vidx) = o;
}

// ---------------------------------------------------------------------------
extern "C" void kernel_launch(void* const* d_in, const int* in_sizes, int n_in,
                              void* d_out, int out_size, void* d_ws, size_t ws_size,
                              hipStream_t stream) {
  const float* h = (const float*)d_in[0];
  const int* adj = (const int*)d_in[1];
  const float* W = (const float*)d_in[2];
  const float* av = (const float*)d_in[3];
  float* out = (float*)d_out;
  char* ws = (char*)d_ws;

  u16* WT = (u16*)ws;                                        // 128 KB
  float* wa = (float*)(ws + (256ull << 10));                 // 4 KB
  u16* WhT = (u16*)(ws + (512ull << 10));                    // 2 MB
  float* Wh1 = (float*)(ws + (512ull << 10) + (2ull << 20));
  float* Wh2 = (float*)(ws + (512ull << 10) + (2ull << 20) + (32ull << 10));
  float* sp = (float*)(ws + (512ull << 10) + (2ull << 20) + (64ull << 10));
  float* accp = (float*)(ws + (512ull << 10) + (2ull << 20) + (320ull << 10));

  prep_k<<<16, 256, 0, stream>>>(W, av, WT, wa);
  gemm_wh<<<N_NODES / 32, 256, 0, stream>>>(h, WT, wa, WhT, Wh1, Wh2);
  gat_main<<<(N_NODES / 64) * JS, 256, 0, stream>>>(adj, Wh1, Wh2, WhT, accp, sp);
  finalize_k<<<(N_NODES * F_OUT) / 1024, 256, 0, stream>>>(accp, sp, out);
}

// Round 10
// 123.853 us; speedup vs baseline: 1.5934x; 1.5934x over previous
//
#include <hip/hip_runtime.h>
#include <stdint.h>

typedef float f32x4 __attribute__((ext_vector_type(4)));
typedef __bf16 bf16x8 __attribute__((ext_vector_type(8)));
typedef unsigned short u16;
typedef unsigned int u32;
typedef unsigned long long u64;

#define N_NODES 8192
#define F_IN 512
#define F_OUT 128
#define LRA 0.2f
#define JS 8
#define JLEN (N_NODES / JS)   // 1024
#define NU (JLEN / 32)        // 32 units of 32 cols

__device__ __forceinline__ u16 f32_to_bf16(float f) {
  union { float f; u32 u; } v; v.f = f;
  u32 u = v.u;
  u += 0x7fffu + ((u >> 16) & 1u);   // round-to-nearest-even
  return (u16)(u >> 16);
}
__device__ __forceinline__ float dot4(f32x4 a, f32x4 b) {
  return a[0] * b[0] + a[1] * b[1] + a[2] * b[2] + a[3] * b[3];
}

// ---------------------------------------------------------------------------
// prep_k: WT[d][k] = bf16(W[k][d])  (128 x 512), and wa = [W@a1 ; W@a2] fp32.
// ---------------------------------------------------------------------------
__global__ __launch_bounds__(256) void prep_k(
    const float* __restrict__ W, const float* __restrict__ av,
    u16* __restrict__ WT, float* __restrict__ wa) {
  __shared__ u16 Ts[F_OUT][40];
  const int t = threadIdx.x, kc = (int)blockIdx.x * 32;
  {
    const int k = t >> 3, dof = (t & 7) * 16;
#pragma unroll
    for (int q = 0; q < 4; ++q) {
      f32x4 v = *(const f32x4*)&W[(size_t)(kc + k) * F_OUT + dof + q * 4];
#pragma unroll
      for (int e = 0; e < 4; ++e) Ts[dof + q * 4 + e][k] = f32_to_bf16(v[e]);
    }
  }
  __syncthreads();
  {
    const int d = t >> 1, kh = (t & 1) * 16;
    uint4 o0 = *(uint4*)&Ts[d][kh];
    uint4 o1 = *(uint4*)&Ts[d][kh + 8];
    *(uint4*)&WT[(size_t)d * F_IN + kc + kh] = o0;
    *(uint4*)&WT[(size_t)d * F_IN + kc + kh + 8] = o1;
  }
  {
    const int kl = t >> 3, l8 = t & 7;
    const float* wrow = &W[(size_t)(kc + kl) * F_OUT];
    float s1 = 0.f, s2 = 0.f;
#pragma unroll
    for (int q = 0; q < 2; ++q) {
      int dd = l8 * 16 + q * 8;
      f32x4 w0 = *(const f32x4*)&wrow[dd];
      f32x4 w1 = *(const f32x4*)&wrow[dd + 4];
      s1 += dot4(w0, *(const f32x4*)&av[dd]) + dot4(w1, *(const f32x4*)&av[dd + 4]);
      s2 += dot4(w0, *(const f32x4*)&av[F_OUT + dd]) + dot4(w1, *(const f32x4*)&av[F_OUT + dd + 4]);
    }
#pragma unroll
    for (int m = 1; m <= 4; m <<= 1) {
      s1 += __shfl_xor(s1, m, 64);
      s2 += __shfl_xor(s2, m, 64);
    }
    if (l8 == 0) { wa[kc + kl] = s1; wa[F_IN + kc + kl] = s2; }
  }
}

// ---------------------------------------------------------------------------
// gemm_wh: Wh = h @ W via 16x16x32 bf16 MFMA. Output in FRAG-LINEAR layout:
//   vf[((u*8 + dt)*64 + lane)*8 + e] = bf16( Wh[u*32 + (lane>>4)*8 + e]
//                                               [dt*16 + (lane&15)] )
// i.e. exactly the per-lane B-fragment gat_main needs -> gat's V loads are
// single b128 at base+lane*16 (1KB contiguous per wave-instr, zero scatter).
// Wh1/Wh2 computed EXACTLY in fp32 as h @ (W@a) fused into A-staging.
// ---------------------------------------------------------------------------
__global__ __launch_bounds__(256) void gemm_wh(
    const float* __restrict__ h, const u16* __restrict__ WT,
    const float* __restrict__ wa,
    u16* __restrict__ vf, float* __restrict__ Wh1, float* __restrict__ Wh2) {
  __shared__ u16 Ab[2][32][80];
  __shared__ u16 Bs[2][F_OUT][80];
  __shared__ float stash[32][133];
  const int t = threadIdx.x;
  const int i0 = (int)blockIdx.x * 32;
  const int w = t >> 6, l = t & 63, r = l & 15, oct = l >> 4;
  const int mrow = (w & 1) * 16, ncol = (w >> 1) * 64;
  const int ar = t >> 3, ak = (t & 7) * 8;
  const int br = t >> 1, bk = (t & 1) * 32;

  const float* hrow = &h[(size_t)(i0 + ar) * F_IN + ak];
  const u16* wtrow = &WT[(size_t)br * F_IN + bk];
  const float* wap = &wa[ak];
  const float* wbp = &wa[F_IN + ak];

  f32x4 acc[4];
#pragma unroll
  for (int nf = 0; nf < 4; ++nf) acc[nf] = (f32x4){0.f, 0.f, 0.f, 0.f};
  float s1 = 0.f, s2 = 0.f;

  f32x4 ra0, ra1;
  uint4 rb[4];

#define STORE_A(B)                                                        \
  { u32 p0 = f32_to_bf16(ra0[0]) | ((u32)f32_to_bf16(ra0[1]) << 16);      \
    u32 p1 = f32_to_bf16(ra0[2]) | ((u32)f32_to_bf16(ra0[3]) << 16);      \
    u32 p2 = f32_to_bf16(ra1[0]) | ((u32)f32_to_bf16(ra1[1]) << 16);      \
    u32 p3 = f32_to_bf16(ra1[2]) | ((u32)f32_to_bf16(ra1[3]) << 16);      \
    uint4 v; v.x = p0; v.y = p1; v.z = p2; v.w = p3;                      \
    *(uint4*)&Ab[B][ar][ak] = v; }
#define STORE_B(B)                                                        \
  { *(uint4*)&Bs[B][br][bk + 0]  = rb[0];                                 \
    *(uint4*)&Bs[B][br][bk + 8]  = rb[1];                                 \
    *(uint4*)&Bs[B][br][bk + 16] = rb[2];                                 \
    *(uint4*)&Bs[B][br][bk + 24] = rb[3]; }

  ra0 = *(const f32x4*)&hrow[0];
  ra1 = *(const f32x4*)&hrow[4];
#pragma unroll
  for (int j = 0; j < 4; ++j) rb[j] = *(const uint4*)&wtrow[j * 8];
  s1 += dot4(ra0, *(const f32x4*)&wap[0]) + dot4(ra1, *(const f32x4*)&wap[4]);
  s2 += dot4(ra0, *(const f32x4*)&wbp[0]) + dot4(ra1, *(const f32x4*)&wbp[4]);
  STORE_A(0); STORE_B(0);
  __syncthreads();

#pragma unroll
  for (int it = 0; it < 8; ++it) {
    const int buf = it & 1;
    if (it < 7) {
      const int kc = (it + 1) * 64;
      ra0 = *(const f32x4*)&hrow[kc];
      ra1 = *(const f32x4*)&hrow[kc + 4];
#pragma unroll
      for (int j = 0; j < 4; ++j) rb[j] = *(const uint4*)&wtrow[kc + j * 8];
      s1 += dot4(ra0, *(const f32x4*)&wap[kc]) + dot4(ra1, *(const f32x4*)&wap[kc + 4]);
      s2 += dot4(ra0, *(const f32x4*)&wbp[kc]) + dot4(ra1, *(const f32x4*)&wbp[kc + 4]);
    }
#pragma unroll
    for (int ks = 0; ks < 2; ++ks) {
      bf16x8 af = *(bf16x8*)&Ab[buf][mrow + r][ks * 32 + oct * 8];
#pragma unroll
      for (int nf = 0; nf < 4; ++nf) {
        bf16x8 bfv = *(bf16x8*)&Bs[buf][ncol + nf * 16 + r][ks * 32 + oct * 8];
        acc[nf] = __builtin_amdgcn_mfma_f32_16x16x32_bf16(af, bfv, acc[nf], 0, 0, 0);
      }
    }
    if (it < 7) {
      STORE_A(buf ^ 1); STORE_B(buf ^ 1);
      __syncthreads();
    }
  }
#undef STORE_A
#undef STORE_B

#pragma unroll
  for (int m = 1; m <= 4; m <<= 1) {
    s1 += __shfl_xor(s1, m, 64);
    s2 += __shfl_xor(s2, m, 64);
  }
  if ((t & 7) == 0) { Wh1[i0 + ar] = s1; Wh2[i0 + ar] = s2; }

  // ---- stash fp32 tile, then emit frag-linear bf16 Vf ----
#pragma unroll
  for (int nf = 0; nf < 4; ++nf)
#pragma unroll
    for (int rr = 0; rr < 4; ++rr)
      stash[mrow + oct * 4 + rr][ncol + nf * 16 + r] = acc[nf][rr];
  __syncthreads();
  {
    const int half = t >> 6;           // 0..3
#pragma unroll
    for (int s = 0; s < 2; ++s) {
      const int dt = half * 2 + s;     // d-tile 0..7
      u32 pk[4];
#pragma unroll
      for (int e2 = 0; e2 < 4; ++e2) {
        u32 lo = f32_to_bf16(stash[oct * 8 + 2 * e2][dt * 16 + r]);
        u32 hi = f32_to_bf16(stash[oct * 8 + 2 * e2 + 1][dt * 16 + r]);
        pk[e2] = lo | (hi << 16);
      }
      uint4 v; v.x = pk[0]; v.y = pk[1]; v.z = pk[2]; v.w = pk[3];
      *(uint4*)(vf + ((size_t)((i0 / 32) * 8 + dt) * 64 + l) * 8) = v;
    }
  }
}

// ---------------------------------------------------------------------------
// gat_main v10: all hot-loop global loads COALESCED.
//  - V: frag-linear vf -> one b128 per (unit,d-tile) at base+lane*16
//    (1KB contiguous/instr). Ping-pong prefetched 1 unit ahead (L2).
//  - adj: ballot form. 8 loads per 16x32 tile, each 64 lanes x 4B = 256B
//    contiguous (2 full lines): lane l reads adj[row+(l>>5)][jc+(l&31)].
//    __ballot(x!=0) -> 8 uniform u64 masks; each lane extracts its 8
//    A-frag bits via a cndmask tree. Raw ints prefetched 3 units (~900cy)
//    ahead in 4 rotating named register sets.
//  - barrier-free (one __syncthreads for w2s); P built in A-frag registers;
//    denominator accumulated from the SAME rounded bf16 values.
// ---------------------------------------------------------------------------
__global__ __launch_bounds__(256) void gat_main(
    const int* __restrict__ adj, const float* __restrict__ Wh1,
    const float* __restrict__ Wh2, const u16* __restrict__ vf,
    float* __restrict__ accp, float* __restrict__ sp) {
  __shared__ float w2s[JLEN];

  const int t = threadIdx.x;
  const int jsi = (int)blockIdx.x & (JS - 1);   // j-slice -> XCD L2 pinning
  const int bi = (int)blockIdx.x >> 3;
  const int j0 = jsi * JLEN;
  const int w = t >> 6, l = t & 63, r = l & 15, oct = l >> 4;
  const int i0w = bi * 64 + w * 16;             // wave's 16-row strip

  for (int k = t * 4; k < JLEN; k += 1024)
    *(f32x4*)&w2s[k] = *(const f32x4*)&Wh2[j0 + k];
  const float cI = Wh1[i0w + r];
  __syncthreads();                              // the only barrier (w2s)

  // coalesced adj base: lane covers row (l>>5), col (l&31) of each 2-row pair
  const int* abase = &adj[(size_t)(i0w + (l >> 5)) * N_NODES + j0 + (l & 31)];
  // frag-linear V base for this j-slice
  const u16* vfb = vf + (size_t)(jsi * NU) * 8 * 512 + (size_t)l * 8;

  f32x4 acc[8];
#pragma unroll
  for (int nf = 0; nf < 8; ++nf) acc[nf] = (f32x4){0.f, 0.f, 0.f, 0.f};
  float sden = 0.f;

  bf16x8 bvA[8], bvB[8];
  int A0[8], A1[8], A2[8], A3[8];

#define LOAD_ADJ(SET, K) do {                                               \
    const int* ap_ = abase + (size_t)(K) * 32;                              \
    _Pragma("unroll")                                                       \
    for (int p = 0; p < 8; ++p)                                             \
      SET[p] = ap_[(size_t)(2 * p) * N_NODES];                              \
  } while (0)

#define LOAD_BV(BV, K) do {                                                 \
    _Pragma("unroll")                                                       \
    for (int dt = 0; dt < 8; ++dt)                                          \
      BV[dt] = *(const bf16x8*)(vfb + (size_t)((K) * 8 + dt) * 512);        \
  } while (0)

#define COMPUTE(SET, K, BV) do {                                            \
    u64 bal_[8];                                                            \
    _Pragma("unroll")                                                       \
    for (int p = 0; p < 8; ++p) bal_[p] = __ballot(SET[p] != 0);            \
    u32 m32_ = 0;                                                           \
    _Pragma("unroll")                                                       \
    for (int p = 0; p < 8; ++p) {                                           \
      u32 h_ = (r & 1) ? (u32)(bal_[p] >> 32) : (u32)bal_[p];               \
      m32_ |= ((r >> 1) == p) ? h_ : 0u;                                    \
    }                                                                       \
    const u32 mb_ = m32_ >> (oct * 8);                                      \
    f32x4 wv0 = *(const f32x4*)&w2s[(K) * 32 + oct * 8];                    \
    f32x4 wv1 = *(const f32x4*)&w2s[(K) * 32 + oct * 8 + 4];                \
    u32 pk_[4];                                                             \
    _Pragma("unroll")                                                       \
    for (int q = 0; q < 4; ++q) {                                           \
      float wA_ = (q < 2) ? wv0[q * 2] : wv1[(q - 2) * 2];                  \
      float wB_ = (q < 2) ? wv0[q * 2 + 1] : wv1[(q - 2) * 2 + 1];          \
      float xA_ = cI + wA_; xA_ = fmaxf(xA_, LRA * xA_);                    \
      float xB_ = cI + wB_; xB_ = fmaxf(xB_, LRA * xB_);                    \
      float pA_ = (mb_ & (1u << (2 * q))) ? __expf(xA_) : 0.f;              \
      float pB_ = (mb_ & (2u << (2 * q))) ? __expf(xB_) : 0.f;              \
      u32 uA_ = f32_to_bf16(pA_), uB_ = f32_to_bf16(pB_);                   \
      union { u32 u; float f; } fA_, fB_;                                   \
      fA_.u = uA_ << 16; fB_.u = uB_ << 16;                                 \
      sden += fA_.f + fB_.f;                                                \
      pk_[q] = uA_ | (uB_ << 16);                                           \
    }                                                                       \
    union { u32 u[4]; bf16x8 v; } cv_;                                      \
    cv_.u[0] = pk_[0]; cv_.u[1] = pk_[1];                                   \
    cv_.u[2] = pk_[2]; cv_.u[3] = pk_[3];                                   \
    _Pragma("unroll")                                                       \
    for (int nf = 0; nf < 8; ++nf)                                          \
      acc[nf] = __builtin_amdgcn_mfma_f32_16x16x32_bf16(cv_.v, BV[nf], acc[nf], 0, 0, 0); \
  } while (0)

  // STEP k: issue bv(k+1), adj(k+3); compute unit k from regs loaded earlier.
#define STEP(K, SC, SP, BVC, BVN) do {                                      \
    LOAD_BV(BVN, ((K) + 1 < NU) ? (K) + 1 : 0);                             \
    __builtin_amdgcn_sched_barrier(0);                                      \
    LOAD_ADJ(SP, ((K) + 3 < NU) ? (K) + 3 : 0);                             \
    __builtin_amdgcn_sched_barrier(0);                                      \
    COMPUTE(SC, K, BVC);                                                    \
  } while (0)

  // prologue: adj units 0,1,2 ; bv unit 0
  LOAD_ADJ(A0, 0);
  LOAD_ADJ(A1, 1);
  LOAD_ADJ(A2, 2);
  LOAD_BV(bvA, 0);

#pragma unroll 1
  for (int u = 0; u < NU; u += 4) {
    STEP(u + 0, A0, A3, bvA, bvB);
    STEP(u + 1, A1, A0, bvB, bvA);
    STEP(u + 2, A2, A1, bvA, bvB);
    STEP(u + 3, A3, A2, bvB, bvA);
  }
#undef STEP
#undef COMPUTE
#undef LOAD_BV
#undef LOAD_ADJ

  // ---- denominator: row r full sum across the 4 oct groups ----
  {
    float s = sden;
    s += __shfl_xor(s, 16, 64);
    s += __shfl_xor(s, 32, 64);
    if (l < 16) sp[(size_t)jsi * N_NODES + i0w + l] = s;
  }

  // ---- numerator partials: C frag col(d)=nf*16+r, row=oct*4+reg ----
  float* apw = &accp[((size_t)jsi * N_NODES + i0w + oct * 4) * F_OUT + r];
#pragma unroll
  for (int nf = 0; nf < 8; ++nf)
#pragma unroll
    for (int rr = 0; rr < 4; ++rr)
      apw[(size_t)rr * F_OUT + nf * 16] = acc[nf][rr];
}

// ---------------------------------------------------------------------------
// finalize: reduce j-split partials (f32x4 vectorized), divide, ELU.
// ---------------------------------------------------------------------------
__global__ __launch_bounds__(256) void finalize_k(
    const float* __restrict__ accp, const float* __restrict__ sp,
    float* __restrict__ out) {
  const int vidx = (int)blockIdx.x * 256 + threadIdx.x;   // f32x4 index
  const int i = vidx >> 5;                                // node row
  f32x4 num = (f32x4){0.f, 0.f, 0.f, 0.f};
  float den = 0.f;
#pragma unroll
  for (int s = 0; s < JS; ++s) {
    num += *((const f32x4*)accp + (size_t)s * (N_NODES * F_OUT / 4) + vidx);
    den += sp[(size_t)s * N_NODES + i];
  }
  f32x4 o;
#pragma unroll
  for (int c = 0; c < 4; ++c) {
    float x = num[c] / den;
    o[c] = x > 0.f ? x : expm1f(x);
  }
  *((f32x4*)out + vidx) = o;
}

// ---------------------------------------------------------------------------
extern "C" void kernel_launch(void* const* d_in, const int* in_sizes, int n_in,
                              void* d_out, int out_size, void* d_ws, size_t ws_size,
                              hipStream_t stream) {
  const float* h = (const float*)d_in[0];
  const int* adj = (const int*)d_in[1];
  const float* W = (const float*)d_in[2];
  const float* av = (const float*)d_in[3];
  float* out = (float*)d_out;
  char* ws = (char*)d_ws;

  u16* WT = (u16*)ws;                                        // 128 KB
  float* wa = (float*)(ws + (256ull << 10));                 // 4 KB
  u16* vf = (u16*)(ws + (512ull << 10));                     // 2 MB frag-linear V
  float* Wh1 = (float*)(ws + (512ull << 10) + (2ull << 20));
  float* Wh2 = (float*)(ws + (512ull << 10) + (2ull << 20) + (32ull << 10));
  float* sp = (float*)(ws + (512ull << 10) + (2ull << 20) + (64ull << 10));
  float* accp = (float*)(ws + (512ull << 10) + (2ull << 20) + (320ull << 10));

  prep_k<<<16, 256, 0, stream>>>(W, av, WT, wa);
  gemm_wh<<<N_NODES / 32, 256, 0, stream>>>(h, WT, wa, vf, Wh1, Wh2);
  gat_main<<<(N_NODES / 64) * JS, 256, 0, stream>>>(adj, Wh1, Wh2, vf, accp, sp);
  finalize_k<<<(N_NODES * F_OUT) / 1024, 256, 0, stream>>>(accp, sp, out);
}